// Round 3
// baseline (43019.846 us; speedup 1.0000x reference)
//
#include <hip/hip_runtime.h>
#include <hip/hip_bf16.h>
#include <hip/hip_cooperative_groups.h>

namespace cg = cooperative_groups;

#define UNITS 1024
#define BATCH 128
#define SEQ   512
#define LROW  1032   // LDS row stride in shorts (2064 B): row base advances 16 B in
                     // bank space -> a wave's 64 b128 lanes spread over all 8 bank-quads
                     // (8 lanes/quad = the 1 KiB/wave floor)

typedef short bf16x8 __attribute__((ext_vector_type(8)));
typedef float f32x4  __attribute__((ext_vector_type(4)));

// ---- fp32 <-> bf16 split helpers (RNE) ----
__device__ __forceinline__ unsigned short f2bf(float v) {
    union { float f; unsigned u; } x; x.f = v;
    unsigned r = x.u + 0x7fffu + ((x.u >> 16) & 1u);
    return (unsigned short)(r >> 16);
}
__device__ __forceinline__ float bf2f(unsigned short s) {
    union { unsigned u; float f; } x; x.u = ((unsigned)s) << 16;
    return x.f;
}
__device__ __forceinline__ float sigmf(float v) { return 1.0f / (1.0f + expf(-v)); }

// A: lane holds A[row=l&15][k=8*(l>>4)+j]; B: B[k=8*(l>>4)+j][col=l&15];
// D: D[row=4*(l>>4)+r][col=l&15]  (m89/m97-verified layouts)
__device__ __forceinline__ f32x4 mfma_bf16(bf16x8 a, bf16x8 b, f32x4 c) {
    asm("v_mfma_f32_16x16x32_bf16 %0, %1, %2, %0" : "+v"(c) : "v"(a), "v"(b));
    return c;
}

// ============ prep: transpose + dual-bf16 split of weights ============
// virtual source columns: c in [0,1024) -> Wh ; c in [1024,5120) -> gate col
// cc=c-1024, g=cc&3 (f,i,c,o), j=cc>>2  => gate-interleaved so one WG owns
// all 4 gates of its 4 h-columns.
__global__ void prep_split(const float* __restrict__ Wh,
                           const float* __restrict__ Wf,
                           const float* __restrict__ Wi,
                           const float* __restrict__ Wc,
                           const float* __restrict__ Wo,
                           unsigned short* __restrict__ WhT_hi,
                           unsigned short* __restrict__ WhT_lo,
                           unsigned short* __restrict__ WcT_hi,
                           unsigned short* __restrict__ WcT_lo)
{
    __shared__ float tile[32][33];
    const int ct = blockIdx.x;   // 0..159
    const int kt = blockIdx.y;   // 0..31
    const int tx = threadIdx.x;  // 0..31
    const int ty = threadIdx.y;  // 0..7
    const int cbase = ct * 32, kbase = kt * 32;

    #pragma unroll
    for (int i = 0; i < 4; ++i) {
        int kl = ty + i * 8;
        int k  = kbase + kl;
        int c  = cbase + tx;
        float v;
        if (c < UNITS) {
            v = Wh[k * UNITS + c];
        } else {
            int cc = c - UNITS;
            int g = cc & 3, j = cc >> 2;
            const float* W = (g == 0) ? Wf : (g == 1) ? Wi : (g == 2) ? Wc : Wo;
            v = W[k * UNITS + j];
        }
        tile[kl][tx] = v;
    }
    __syncthreads();
    #pragma unroll
    for (int i = 0; i < 4; ++i) {
        int cl = ty + i * 8;
        int c  = cbase + cl;
        int k  = kbase + tx;
        float v = tile[tx][cl];
        unsigned short hi = f2bf(v);
        unsigned short lo = f2bf(v - bf2f(hi));
        if (c < UNITS) {
            WhT_hi[c * UNITS + k] = hi;
            WhT_lo[c * UNITS + k] = lo;
        } else {
            int cc = c - UNITS;
            WcT_hi[cc * UNITS + k] = hi;
            WcT_lo[cc * UNITS + k] = lo;
        }
    }
}

// ============ persistent LSTM loop, cooperative ============
// grid 256 x 256thr, 1 WG/CU. ALL weights LDS-resident (grid.sync's agent-scope
// fence invalidates per-XCD L2 every step -> global weight reads would refetch
// from HBM each step; that was 5.7 MB/step = the entire 41 ms of round 2).
//   phase1: inp = h@Wh + E[x_t] + b   (WG: 32-row block x 16 Wh-cols; wave =
//           (rowtile, K-half); Wh tile hi/lo in LDS; LDS reduce across K-halves)
//   phase2: G = inp@Wcat (gate-interleaved, 16 gate-cols = 4 h-cols per WG;
//           wave owns 32 rows full-K); epilogue: LSTM update with h kept in
//           REGISTERS (static thread ownership), emit y, write h_hi/h_lo.
__global__ void __launch_bounds__(256, 1)
lstm_persistent(const int* __restrict__ x, const float* __restrict__ E,
                const float* __restrict__ bvec,
                const float* __restrict__ bfv, const float* __restrict__ biv,
                const float* __restrict__ bcv, const float* __restrict__ bov,
                const unsigned short* __restrict__ WhT_hi, const unsigned short* __restrict__ WhT_lo,
                const unsigned short* __restrict__ WcT_hi, const unsigned short* __restrict__ WcT_lo,
                unsigned short* __restrict__ h_hi, unsigned short* __restrict__ h_lo,
                unsigned short* __restrict__ inp_hi, unsigned short* __restrict__ inp_lo,
                float* __restrict__ out)
{
    __shared__ unsigned short lwh_h[16 * LROW];   // 33 KB  Wh tile hi (16 cols x 1024 k)
    __shared__ unsigned short lwh_l[16 * LROW];   // 33 KB  Wh tile lo
    __shared__ unsigned short lwc_h[16 * LROW];   // 33 KB  Wcat tile hi (16 gate-cols)
    __shared__ unsigned short lwc_l[16 * LROW];   // 33 KB  Wcat tile lo
    __shared__ __align__(16) float sc[4][32][20]; // 10 KB  reduce/epilogue scratch

    cg::grid_group grid = cg::this_grid();

    const int wg = blockIdx.x, tid = threadIdx.x;
    const int wave = tid >> 6, lane = tid & 63;
    const int l16 = lane & 15, lk = lane >> 4;

    // phase-1 tile: rows 32*m1..+31, Wh-cols cb1..cb1+15
    const int m1  = wg >> 6;          // 0..3
    const int cb1 = (wg & 63) * 16;
    // phase-2 tile: all 128 rows, gate-cols cb2..cb2+15 (= h-cols wg*4..wg*4+3)
    const int cb2 = wg * 16;

    // ---- stage all weight tiles into LDS (once) ----
    {
        const uint4* s0 = (const uint4*)(WhT_hi + (size_t)cb1 * UNITS);
        const uint4* s1 = (const uint4*)(WhT_lo + (size_t)cb1 * UNITS);
        const uint4* s2 = (const uint4*)(WcT_hi + (size_t)cb2 * UNITS);
        const uint4* s3 = (const uint4*)(WcT_lo + (size_t)cb2 * UNITS);
        uint4* d0 = (uint4*)lwh_h; uint4* d1 = (uint4*)lwh_l;
        uint4* d2 = (uint4*)lwc_h; uint4* d3 = (uint4*)lwc_l;
        for (int idx = tid; idx < 16 * 128; idx += 256) {
            int r = idx >> 7, o = idx & 127;   // row, 16B chunk
            int d = r * 129 + o;               // 129 uint4 = 2064 B row stride
            d0[d] = s0[idx]; d1[d] = s1[idx];
            d2[d] = s2[idx]; d3[d] = s3[idx];
        }
    }
    // ---- zero the recurrent-state broadcast planes ----
    for (int i = wg * 256 + tid; i < BATCH * UNITS; i += 256 * 256) {
        h_hi[i] = 0; h_lo[i] = 0;
    }
    // ---- h f32 lives in registers: thread owns (rows wave*32+{idx>>2}, col wg*4+{idx&3}) ----
    float hreg0 = 0.0f, hreg1 = 0.0f;

    grid.sync();

    #pragma unroll 1
    for (int t = 0; t < SEQ; ++t) {
        // ================= phase 1: inp = h@Wh + E[x_t] + b =================
        {
            const int rt1 = wave & 1;          // 16-row subtile
            const int kh  = (wave >> 1) * 512; // K-half
            f32x4 a0 = {0,0,0,0}, a1 = {0,0,0,0}, a2 = {0,0,0,0};
            const unsigned short* pah = h_hi + (m1 * 32 + rt1 * 16 + l16) * UNITS + kh + lk * 8;
            const unsigned short* pal = h_lo + (m1 * 32 + rt1 * 16 + l16) * UNITS + kh + lk * 8;
            const char* qh = (const char*)lwh_h;
            const char* ql = (const char*)lwh_l;
            const int bb = l16 * 2064 + kh * 2 + lk * 16;
            asm volatile("s_nop 3");   // VALU acc-init -> MFMA SrcC hazard guard
            #pragma unroll 4
            for (int ks = 0; ks < 16; ++ks) {
                bf16x8 ah = *(const bf16x8*)pah; pah += 32;
                bf16x8 al = *(const bf16x8*)pal; pal += 32;
                bf16x8 bh = *(const bf16x8*)(qh + bb + ks * 64);
                bf16x8 bl = *(const bf16x8*)(ql + bb + ks * 64);
                a0 = mfma_bf16(ah, bh, a0);
                a1 = mfma_bf16(ah, bl, a1);
                a2 = mfma_bf16(al, bh, a2);
            }
            asm volatile("s_nop 7\n\ts_nop 7" : "+v"(a0), "+v"(a1), "+v"(a2));
            #pragma unroll
            for (int r = 0; r < 4; ++r)
                sc[wave][lk * 4 + r][l16] = a0[r] + a1[r] + a2[r];
        }
        __syncthreads();
        if (wave < 2) {   // waves 0,1: reduce K-halves, add E[x]+b, split, store
            const int Rb = m1 * 32 + wave * 16;
            #pragma unroll
            for (int it = 0; it < 4; ++it) {
                int idx = it * 64 + lane;
                int rr = idx >> 4, cc = idx & 15;
                float v = sc[wave][rr][cc] + sc[wave + 2][rr][cc];
                int row = Rb + rr, col = cb1 + cc;
                int xv = x[row * SEQ + t];
                v += E[(size_t)xv * UNITS + col] + bvec[col];
                unsigned short hi = f2bf(v);
                unsigned short lo = f2bf(v - bf2f(hi));
                inp_hi[row * UNITS + col] = hi;
                inp_lo[row * UNITS + col] = lo;
            }
        }
        grid.sync();

        // ============ phase 2: gates = inp@Wcat ; LSTM update ; emit y ============
        {
            f32x4 c0a={0,0,0,0}, c0b={0,0,0,0}, c0c={0,0,0,0};
            f32x4 c1a={0,0,0,0}, c1b={0,0,0,0}, c1c={0,0,0,0};
            const unsigned short* pa0h = inp_hi + (wave * 32 + l16) * UNITS + lk * 8;
            const unsigned short* pa0l = inp_lo + (wave * 32 + l16) * UNITS + lk * 8;
            const unsigned short* pa1h = pa0h + 16 * UNITS;
            const unsigned short* pa1l = pa0l + 16 * UNITS;
            const char* qh = (const char*)lwc_h;
            const char* ql = (const char*)lwc_l;
            const int bb = l16 * 2064 + lk * 16;
            asm volatile("s_nop 3");   // VALU acc-init -> MFMA SrcC hazard guard
            #pragma unroll 2
            for (int ks = 0; ks < 32; ++ks) {
                bf16x8 bh  = *(const bf16x8*)(qh + bb + ks * 64);
                bf16x8 bl  = *(const bf16x8*)(ql + bb + ks * 64);
                bf16x8 a0h = *(const bf16x8*)pa0h; pa0h += 32;
                bf16x8 a0l = *(const bf16x8*)pa0l; pa0l += 32;
                bf16x8 a1h = *(const bf16x8*)pa1h; pa1h += 32;
                bf16x8 a1l = *(const bf16x8*)pa1l; pa1l += 32;
                c0a = mfma_bf16(a0h, bh, c0a);
                c1a = mfma_bf16(a1h, bh, c1a);
                c0b = mfma_bf16(a0h, bl, c0b);
                c1b = mfma_bf16(a1h, bl, c1b);
                c0c = mfma_bf16(a0l, bh, c0c);
                c1c = mfma_bf16(a1l, bh, c1c);
            }
            asm volatile("s_nop 7\n\ts_nop 7"
                         : "+v"(c0a), "+v"(c0b), "+v"(c0c), "+v"(c1a), "+v"(c1b), "+v"(c1c));
            #pragma unroll
            for (int r = 0; r < 4; ++r) {
                sc[wave][lk * 4 + r][l16]      = c0a[r] + c0b[r] + c0c[r];
                sc[wave][16 + lk * 4 + r][l16] = c1a[r] + c1b[r] + c1c[r];
            }
        }
        __syncthreads();
        {
            const int jb = wg * 4;   // h-col base
            // it = 0: rows wave*32 + (lane>>2), col jb + (lane&3)
            {
                int rr = lane >> 2, jj = lane & 3;
                f32x4 g4 = *(const f32x4*)&sc[wave][rr][jj * 4];   // f,i,c,o
                int col = jb + jj;
                int row = wave * 32 + rr;
                float ff = sigmf(g4[0] + bfv[col]);
                float ii = sigmf(g4[1] + biv[col]);
                float cv = tanhf (g4[2] + bcv[col]);
                float oo = sigmf(g4[3] + bov[col]);
                float h1 = ff * hreg0 + ii * cv;
                hreg0 = h1;
                float y  = oo * tanhf(h1);
                unsigned short hh = f2bf(h1);
                h_hi[row * UNITS + col] = hh;
                h_lo[row * UNITS + col] = f2bf(h1 - bf2f(hh));
                out[((size_t)row * SEQ + t) * UNITS + col] = y;
            }
            // it = 1: rows wave*32 + 16 + (lane>>2)
            {
                int rr = 16 + (lane >> 2), jj = lane & 3;
                f32x4 g4 = *(const f32x4*)&sc[wave][rr][jj * 4];
                int col = jb + jj;
                int row = wave * 32 + rr;
                float ff = sigmf(g4[0] + bfv[col]);
                float ii = sigmf(g4[1] + biv[col]);
                float cv = tanhf (g4[2] + bcv[col]);
                float oo = sigmf(g4[3] + bov[col]);
                float h1 = ff * hreg1 + ii * cv;
                hreg1 = h1;
                float y  = oo * tanhf(h1);
                unsigned short hh = f2bf(h1);
                h_hi[row * UNITS + col] = hh;
                h_lo[row * UNITS + col] = f2bf(h1 - bf2f(hh));
                out[((size_t)row * SEQ + t) * UNITS + col] = y;
            }
        }
        grid.sync();
    }
}

extern "C" void kernel_launch(void* const* d_in, const int* in_sizes, int n_in,
                              void* d_out, int out_size, void* d_ws, size_t ws_size,
                              hipStream_t stream)
{
    const int*   x    = (const int*)d_in[0];
    const float* E    = (const float*)d_in[1];
    const float* Wh   = (const float*)d_in[2];
    const float* bvec = (const float*)d_in[3];
    const float* Wf   = (const float*)d_in[4];
    const float* bfv  = (const float*)d_in[5];
    const float* Wi   = (const float*)d_in[6];
    const float* biv  = (const float*)d_in[7];
    const float* Wc   = (const float*)d_in[8];
    const float* bcv  = (const float*)d_in[9];
    const float* Wo   = (const float*)d_in[10];
    const float* bov  = (const float*)d_in[11];
    float* out = (float*)d_out;

    char* w = (char*)d_ws;
    const size_t SZW = (size_t)UNITS * UNITS * 2;       // one 1024x1024 bf16 plane
    unsigned short* WhT_hi = (unsigned short*)(w);
    unsigned short* WhT_lo = (unsigned short*)(w + SZW);
    unsigned short* WcT_hi = (unsigned short*)(w + 2 * SZW);
    unsigned short* WcT_lo = (unsigned short*)(w + 6 * SZW);
    char* s = w + 10 * SZW;                             // 20 MiB used so far
    unsigned short* hhi  = (unsigned short*)(s);
    unsigned short* hlo  = (unsigned short*)(s + (size_t)BATCH*UNITS*2);
    unsigned short* ihi  = (unsigned short*)(s + (size_t)BATCH*UNITS*4);
    unsigned short* ilo  = (unsigned short*)(s + (size_t)BATCH*UNITS*6);
    // total ws usage ~= 21 MiB

    prep_split<<<dim3(160, 32), dim3(32, 8), 0, stream>>>(
        Wh, Wf, Wi, Wc, Wo, WhT_hi, WhT_lo, WcT_hi, WcT_lo);

    void* args[] = {
        (void*)&x, (void*)&E, (void*)&bvec, (void*)&bfv, (void*)&biv, (void*)&bcv, (void*)&bov,
        (void*)&WhT_hi, (void*)&WhT_lo, (void*)&WcT_hi, (void*)&WcT_lo,
        (void*)&hhi, (void*)&hlo, (void*)&ihi, (void*)&ilo, (void*)&out
    };
    hipLaunchCooperativeKernel(reinterpret_cast<void*>(lstm_persistent),
                               dim3(256), dim3(256), args, 0, stream);
}

// Round 8
// 31294.257 us; speedup vs baseline: 1.3747x; 1.3747x over previous
//
#include <hip/hip_runtime.h>
#include <hip/hip_bf16.h>
#include <hip/hip_cooperative_groups.h>

namespace cg = cooperative_groups;

#define UNITS 1024
#define BATCH 128
#define SEQ   512

typedef short bf16x8 __attribute__((ext_vector_type(8)));
typedef float f32x4  __attribute__((ext_vector_type(4)));

// ---- fp32 <-> bf16 split helpers (RNE) ----
__device__ __forceinline__ unsigned short f2bf(float v) {
    union { float f; unsigned u; } x; x.f = v;
    unsigned r = x.u + 0x7fffu + ((x.u >> 16) & 1u);
    return (unsigned short)(r >> 16);
}
__device__ __forceinline__ float bf2f(unsigned short s) {
    union { unsigned u; float f; } x; x.u = ((unsigned)s) << 16;
    return x.f;
}
__device__ __forceinline__ float sigmf(float v) { return 1.0f / (1.0f + expf(-v)); }

// A: lane holds A[row=l&15][k=8*(l>>4)+j]; B: B[k=8*(l>>4)+j][col=l&15];
// D: D[row=4*(l>>4)+r][col=l&15]
// plain: SrcA/B from memory loads (compiler orders via waitcnt), SrcC from MFMA chain
__device__ __forceinline__ f32x4 mfma_plain(bf16x8 a, bf16x8 b, f32x4 c) {
    asm("v_mfma_f32_16x16x32_bf16 %0, %1, %2, %0" : "+v"(c) : "v"(a), "v"(b));
    return c;
}
// guard: s_nop fused into the SAME asm -> guaranteed >=4 wait states between any
// preceding VALU write of a/b/c and the MFMA read (hazard recognizer can't see
// inline asm; a free-floating s_nop is schedulable away — this one is not).
__device__ __forceinline__ f32x4 mfma_guard(bf16x8 a, bf16x8 b, f32x4 c) {
    asm("s_nop 3\n\tv_mfma_f32_16x16x32_bf16 %0, %1, %2, %0" : "+v"(c) : "v"(a), "v"(b));
    return c;
}

// 8 consecutive f32 -> bf16x8 via v_cvt_pk_bf16_f32 (VALU! consumers must be mfma_guard)
__device__ __forceinline__ bf16x8 cvt8(const float* p) {
    float4 f0 = *(const float4*)p;
    float4 f1 = *(const float4*)(p + 4);
    union { unsigned u[4]; bf16x8 v; } r;
    asm("v_cvt_pk_bf16_f32 %0, %1, %2" : "=v"(r.u[0]) : "v"(f0.x), "v"(f0.y));
    asm("v_cvt_pk_bf16_f32 %0, %1, %2" : "=v"(r.u[1]) : "v"(f0.z), "v"(f0.w));
    asm("v_cvt_pk_bf16_f32 %0, %1, %2" : "=v"(r.u[2]) : "v"(f1.x), "v"(f1.y));
    asm("v_cvt_pk_bf16_f32 %0, %1, %2" : "=v"(r.u[3]) : "v"(f1.z), "v"(f1.w));
    return r.v;
}

// ============ single cooperative kernel: builds its own weight tiles ============
// 256 WGs x 256 thr, 1 WG/CU. Each WG owns 4 h-cols = 16 gate-cols (gate-
// interleaved: gate-col cc = 4*hcol + g, g in {f,i,c,o}).
__global__ void __launch_bounds__(256, 1)
lstm_all(const int* __restrict__ x, const float* __restrict__ E,
         const float* __restrict__ Wh, const float* __restrict__ bvec,
         const float* __restrict__ Wf, const float* __restrict__ Wi,
         const float* __restrict__ Wc, const float* __restrict__ Wo,
         const float* __restrict__ bfv, const float* __restrict__ biv,
         const float* __restrict__ bcv, const float* __restrict__ bov,
         unsigned short* __restrict__ h_hi0, unsigned short* __restrict__ h_lo0,
         unsigned short* __restrict__ h_hi1, unsigned short* __restrict__ h_lo1,
         float* __restrict__ out)
{
    __shared__ unsigned short lwf_h[16 * 1032];   // 33 KB Wfused tile hi (2064 B rows)
    __shared__ unsigned short lwf_l[16 * 1032];   // 33 KB Wfused tile lo
    __shared__ unsigned short lwc_h[16 * 1032];   // 33 KB Wcat tile hi
    __shared__ unsigned short lwc_l[16 * 1032];   // 33 KB Wcat tile lo
    __shared__ __align__(16) float sc[4][32][20]; // 10 KB scratch
    __shared__ float bgl[16];                     // b @ Wcat for this WG's cols

    cg::grid_group grid = cg::this_grid();

    const int wg = blockIdx.x, tid = threadIdx.x;
    const int wave = tid >> 6, lane = tid & 63;
    const int l16 = lane & 15, lk = lane >> 4;

    // XCD-swizzled column ownership
    const int xcd = wg & 7, local = wg >> 3;
    const int hcb = xcd * 128 + local * 4;   // 4 h-cols
    const int gcb = hcb * 4;                 // 16 gate-cols

    const int bbW = l16 * 2064 + lk * 16;    // LDS byte offset (row l16, chunk lk)
    const char* qfh = (const char*)lwf_h;
    const char* qfl = (const char*)lwf_l;
    const char* qch = (const char*)lwc_h;
    const char* qcl = (const char*)lwc_l;

    // ======== S1: build Wcat^T dual tile from f32 gate weights ========
    for (int idx = tid; idx < 16 * 1024; idx += 256) {
        int i = idx >> 10, k = idx & 1023;       // local gate-col, k
        int cc = gcb + i;
        int j = cc >> 2, g = cc & 3;
        const float* W = (g == 0) ? Wf : (g == 1) ? Wi : (g == 2) ? Wc : Wo;
        float v = W[k * UNITS + j];
        unsigned short hi = f2bf(v);
        lwc_h[i * 1032 + k] = hi;
        lwc_l[i * 1032 + k] = f2bf(v - bf2f(hi));
    }
    __syncthreads();

    // ======== S2: bgl[i] = sum_k bvec[k] * Wcat[k][gcb+i] ========
    {
        int i = tid >> 4, seg = tid & 15;
        float s = 0.0f;
        #pragma unroll 4
        for (int k = seg * 64; k < seg * 64 + 64; ++k)
            s += bvec[k] * (bf2f(lwc_h[i * 1032 + k]) + bf2f(lwc_l[i * 1032 + k]));
        ((float*)sc)[i * 16 + seg] = s;
    }
    __syncthreads();
    if (tid < 16) {
        float s = 0.0f;
        #pragma unroll
        for (int q = 0; q < 16; ++q) s += ((float*)sc)[tid * 16 + q];
        bgl[tid] = s;
    }
    __syncthreads();

    // ======== S3: Wfused tile = Wh @ Wcat_tile (dual x dual, 3 products) ========
    // A-fragments are VALU-packed (f2bf) -> ALL MFMAs guarded.
    for (int rt = wave; rt < 64; rt += 4) {
        const int kb = rt * 16;
        const float* pa = Wh + (size_t)(kb + l16) * UNITS + lk * 8;
        f32x4 acc = {0, 0, 0, 0};
        for (int kt = 0; kt < 32; ++kt) {
            float4 w0 = *(const float4*)pa;
            float4 w1 = *(const float4*)(pa + 4);
            pa += 32;
            union { unsigned short u[8]; bf16x8 v; } ah, al;
            float wv[8] = {w0.x, w0.y, w0.z, w0.w, w1.x, w1.y, w1.z, w1.w};
            #pragma unroll
            for (int j = 0; j < 8; ++j) {
                ah.u[j] = f2bf(wv[j]);
                al.u[j] = f2bf(wv[j] - bf2f(ah.u[j]));
            }
            bf16x8 bh = *(const bf16x8*)(qch + bbW + kt * 64);
            bf16x8 bl = *(const bf16x8*)(qcl + bbW + kt * 64);
            acc = mfma_guard(ah.v, bh, acc);
            acc = mfma_guard(ah.v, bl, acc);
            acc = mfma_guard(al.v, bh, acc);
        }
        asm volatile("s_nop 7\n\ts_nop 7" : "+v"(acc));
        #pragma unroll
        for (int r = 0; r < 4; ++r) {
            float v = acc[r];
            unsigned short hi = f2bf(v);
            int o = l16 * 1032 + kb + 4 * lk + r;   // lwf[n][k]
            lwf_h[o] = hi;
            lwf_l[o] = f2bf(v - bf2f(hi));
        }
    }
    __syncthreads();

    // ---- per-thread epilogue statics ----
    const int row_l = lane >> 2;             // 0..15
    const int jj    = lane & 3;              // h-col within WG
    const int col   = hcb + jj;
    const float bf_r = bfv[col] + bgl[4 * jj + 0];
    const float bi_r = biv[col] + bgl[4 * jj + 1];
    const float bc_r = bcv[col] + bgl[4 * jj + 2];
    const float bo_r = bov[col] + bgl[4 * jj + 3];
    float hreg0 = 0.0f, hreg1 = 0.0f;
    const int R0 = wave * 32;

    unsigned short* cur_hi = h_hi0; unsigned short* cur_lo = h_lo0;
    unsigned short* nxt_hi = h_hi1; unsigned short* nxt_lo = h_lo1;

    // ---- prologue: eg for t = 0 (cvt8 inputs -> guarded MFMAs) ----
    f32x4 eg0 = {0,0,0,0}, eg1 = {0,0,0,0};
    {
        int v0 = x[(R0 + l16) * SEQ + 0];
        int v1 = x[(R0 + 16 + l16) * SEQ + 0];
        const float* pE0 = E + (size_t)v0 * UNITS + lk * 8;
        const float* pE1 = E + (size_t)v1 * UNITS + lk * 8;
        #pragma unroll 4
        for (int kt = 0; kt < 32; ++kt) {
            bf16x8 e0 = cvt8(pE0); pE0 += 32;
            bf16x8 e1 = cvt8(pE1); pE1 += 32;
            bf16x8 ch = *(const bf16x8*)(qch + bbW + kt * 64);
            eg0 = mfma_guard(e0, ch, eg0);
            eg1 = mfma_guard(e1, ch, eg1);
        }
        asm volatile("s_nop 7\n\ts_nop 7" : "+v"(eg0), "+v"(eg1));
    }

    #pragma unroll 1
    for (int t = 0; t < SEQ; ++t) {
        const int tt = (t < SEQ - 1) ? t + 1 : SEQ - 1;
        int v0 = x[(R0 + l16) * SEQ + tt];
        int v1 = x[(R0 + 16 + l16) * SEQ + tt];
        const float* pE0 = E + (size_t)v0 * UNITS + lk * 8;
        const float* pE1 = E + (size_t)v1 * UNITS + lk * 8;
        const unsigned short* ph0 = cur_hi + (R0 + l16) * UNITS + lk * 8;
        const unsigned short* pl0 = cur_lo + (R0 + l16) * UNITS + lk * 8;
        const unsigned short* ph1 = ph0 + 16 * UNITS;
        const unsigned short* pl1 = pl0 + 16 * UNITS;

        f32x4 acc0 = eg0, acc1 = eg1;          // G init = eg_t (VALU copy)
        // dependency-bound hazard guard: copy -> s_nop -> first SrcC read
        asm volatile("s_nop 3" : "+v"(acc0), "+v"(acc1));
        f32x4 ne0 = {0,0,0,0}, ne1 = {0,0,0,0};
        #pragma unroll 2
        for (int kt = 0; kt < 32; ++kt) {
            bf16x8 bh = *(const bf16x8*)(qfh + bbW + kt * 64);
            bf16x8 bl = *(const bf16x8*)(qfl + bbW + kt * 64);
            bf16x8 ch = *(const bf16x8*)(qch + bbW + kt * 64);
            bf16x8 a0h = *(const bf16x8*)ph0; ph0 += 32;
            bf16x8 a0l = *(const bf16x8*)pl0; pl0 += 32;
            bf16x8 a1h = *(const bf16x8*)ph1; ph1 += 32;
            bf16x8 a1l = *(const bf16x8*)pl1; pl1 += 32;
            bf16x8 e0  = cvt8(pE0); pE0 += 32;
            bf16x8 e1  = cvt8(pE1); pE1 += 32;
            acc0 = mfma_plain(a0h, bh, acc0);
            acc0 = mfma_plain(a0h, bl, acc0);
            acc0 = mfma_plain(a0l, bh, acc0);
            acc1 = mfma_plain(a1h, bh, acc1);
            acc1 = mfma_plain(a1h, bl, acc1);
            acc1 = mfma_plain(a1l, bh, acc1);
            ne0 = mfma_guard(e0, ch, ne0);     // SrcA is VALU-fresh -> guarded
            ne1 = mfma_guard(e1, ch, ne1);
        }
        asm volatile("s_nop 7\n\ts_nop 7"
                     : "+v"(acc0), "+v"(acc1), "+v"(ne0), "+v"(ne1));
        eg0 = ne0; eg1 = ne1;

        #pragma unroll
        for (int r = 0; r < 4; ++r) {
            sc[wave][lk * 4 + r][l16]      = acc0[r];
            sc[wave][16 + lk * 4 + r][l16] = acc1[r];
        }
        __syncthreads();
        // ---- LSTM update: thread owns (rows R0+row_l, R0+16+row_l) x col ----
        {
            {
                f32x4 g4 = *(const f32x4*)&sc[wave][row_l][jj * 4];   // f,i,c,o
                int row = R0 + row_l;
                float ff = sigmf(g4[0] + bf_r);
                float ii = sigmf(g4[1] + bi_r);
                float cv = tanhf (g4[2] + bc_r);
                float oo = sigmf(g4[3] + bo_r);
                float h1 = ff * hreg0 + ii * cv;
                hreg0 = h1;
                float y = oo * tanhf(h1);
                unsigned short hh = f2bf(h1);
                nxt_hi[row * UNITS + col] = hh;
                nxt_lo[row * UNITS + col] = f2bf(h1 - bf2f(hh));
                out[((size_t)row * SEQ + t) * UNITS + col] = y;
            }
            {
                f32x4 g4 = *(const f32x4*)&sc[wave][16 + row_l][jj * 4];
                int row = R0 + 16 + row_l;
                float ff = sigmf(g4[0] + bf_r);
                float ii = sigmf(g4[1] + bi_r);
                float cv = tanhf (g4[2] + bc_r);
                float oo = sigmf(g4[3] + bo_r);
                float h1 = ff * hreg1 + ii * cv;
                hreg1 = h1;
                float y = oo * tanhf(h1);
                unsigned short hh = f2bf(h1);
                nxt_hi[row * UNITS + col] = hh;
                nxt_lo[row * UNITS + col] = f2bf(h1 - bf2f(hh));
                out[((size_t)row * SEQ + t) * UNITS + col] = y;
            }
        }
        // swap h buffers
        { unsigned short* tp;
          tp = cur_hi; cur_hi = nxt_hi; nxt_hi = tp;
          tp = cur_lo; cur_lo = nxt_lo; nxt_lo = tp; }
        __syncthreads();        // sc reuse + h-store drain before grid barrier
        if (t < SEQ - 1)
            grid.sync();        // one cooperative barrier per step
    }
}

extern "C" void kernel_launch(void* const* d_in, const int* in_sizes, int n_in,
                              void* d_out, int out_size, void* d_ws, size_t ws_size,
                              hipStream_t stream)
{
    const int*   x    = (const int*)d_in[0];
    const float* E    = (const float*)d_in[1];
    const float* Wh   = (const float*)d_in[2];
    const float* bvec = (const float*)d_in[3];
    const float* Wf   = (const float*)d_in[4];
    const float* bfv  = (const float*)d_in[5];
    const float* Wi   = (const float*)d_in[6];
    const float* biv  = (const float*)d_in[7];
    const float* Wc   = (const float*)d_in[8];
    const float* bcv  = (const float*)d_in[9];
    const float* Wo   = (const float*)d_in[10];
    const float* bov  = (const float*)d_in[11];
    float* out = (float*)d_out;

    // ---- workspace: ONLY h double-buffers (1 MB total) ----
    char* w = (char*)d_ws;
    const size_t HP = (size_t)BATCH * UNITS * 2;            // 256 KB h plane
    unsigned short* hhi0 = (unsigned short*)(w);
    unsigned short* hlo0 = (unsigned short*)(w + HP);
    unsigned short* hhi1 = (unsigned short*)(w + 2 * HP);
    unsigned short* hlo1 = (unsigned short*)(w + 3 * HP);
    hipMemsetAsync(w, 0, 2 * HP, stream);   // zero buf0 (buf1 fully written at t=0)

    void* args[] = {
        (void*)&x, (void*)&E, (void*)&Wh, (void*)&bvec,
        (void*)&Wf, (void*)&Wi, (void*)&Wc, (void*)&Wo,
        (void*)&bfv, (void*)&biv, (void*)&bcv, (void*)&bov,
        (void*)&hhi0, (void*)&hlo0, (void*)&hhi1, (void*)&hlo1,
        (void*)&out
    };
    hipLaunchCooperativeKernel(reinterpret_cast<void*>(lstm_all),
                               dim3(256), dim3(256), args, 0, stream);
}